// Round 6
// baseline (224.136 us; speedup 1.0000x reference)
//
#include <hip/hip_runtime.h>
#include <math.h>

// CTC loss, T=1024 B=64 V=256 L=256 (S=513).
// Round 12 = round 11 with the WIN16 token-pasting bug fixed: `BK##0.x`
// is illegal because `0.x` lexes as one pp-number before pasting. The four
// blank-bank registers are now passed as explicit macro parameters (no ##).
// Design unchanged from round 11:
//  k1 (gather+lse): 1024 lse waves (EXACT same partition/arithmetic as
//     previous rounds -> partial[] bit-identical) additionally write exp'd
//     gathered rows ggath[b][t][256] (+ blank bgath[b][t]) to workspace.
//  k2 (recursion): 64 single-wave blocks stream pre-gathered rows through a
//     16-deep NAMED float4 register ring + double-banked blank ring. No LDS
//     staging, no producers, no barriers. Step = 1 coalesced dwordx4 + MACS.
//     Renorm points (t=15,31,...) and all values bit-identical to round-10.
//     k2 also replicates ctc_final EXACTLY via a last-block-finishes atomic.
// If ws_size < ~67.4 MB the host falls back to the round-10 kernels verbatim.

constexpr int V = 256;
constexpr float LN2_F = 0.6931471805599453f;

typedef unsigned uint2v __attribute__((ext_vector_type(2)));

template <int CTRL>
__device__ __forceinline__ float dpp_mov_f(float x) {
    return __int_as_float(__builtin_amdgcn_update_dpp(
        0, __float_as_int(x), CTRL, 0xF, 0xF, true));
}

// whole-wave shift down by 1 lane (lane l reads lane l-1; lane 0 -> 0). VALU.
__device__ __forceinline__ float wave_shr1_f(float x) {
    return __int_as_float(__builtin_amdgcn_update_dpp(
        0, __float_as_int(x), 0x138, 0xF, 0xF, true));  // wave_shr:1
}

__device__ __forceinline__ float wave_max_f(float m) {
    m = fmaxf(m, dpp_mov_f<0xB1>(m));    // quad_perm xor1
    m = fmaxf(m, dpp_mov_f<0x4E>(m));    // quad_perm xor2
    m = fmaxf(m, dpp_mov_f<0x124>(m));   // row_ror:4
    m = fmaxf(m, dpp_mov_f<0x128>(m));   // row_ror:8
#if __has_builtin(__builtin_amdgcn_permlane16_swap) && __has_builtin(__builtin_amdgcn_permlane32_swap)
    uint2v a = __builtin_amdgcn_permlane16_swap(__float_as_uint(m),
                                                __float_as_uint(m), false, false);
    m = fmaxf(__uint_as_float(a.x), __uint_as_float(a.y));
    uint2v b = __builtin_amdgcn_permlane32_swap(__float_as_uint(m),
                                                __float_as_uint(m), false, false);
    m = fmaxf(__uint_as_float(b.x), __uint_as_float(b.y));
#else
    m = fmaxf(m, __shfl_xor(m, 16, 64));
    m = fmaxf(m, __shfl_xor(m, 32, 64));
#endif
    return m;
}

__device__ __forceinline__ float wave_sum_f(float s) {
    s += dpp_mov_f<0xB1>(s);
    s += dpp_mov_f<0x4E>(s);
    s += dpp_mov_f<0x124>(s);
    s += dpp_mov_f<0x128>(s);
#if __has_builtin(__builtin_amdgcn_permlane16_swap) && __has_builtin(__builtin_amdgcn_permlane32_swap)
    uint2v a = __builtin_amdgcn_permlane16_swap(__float_as_uint(s),
                                                __float_as_uint(s), false, false);
    s = __uint_as_float(a.x) + __uint_as_float(a.y);
    uint2v b = __builtin_amdgcn_permlane32_swap(__float_as_uint(s),
                                                __float_as_uint(s), false, false);
    s = __uint_as_float(b.x) + __uint_as_float(b.y);
#else
    s += __shfl_xor(s, 16, 64);
    s += __shfl_xor(s, 32, 64);
#endif
    return s;
}

#define MACS(EB, E1, E3, E5, E7) do {                                  \
    const float c7m = wave_shr1_f(cur7);                               \
    curT = (curT + cur7) * (EB);                                       \
    cur7 = fmaf(sk7, cur5, cur7 + cur6) * (E7);                        \
    cur6 = (cur6 + cur5) * (EB);                                       \
    cur5 = fmaf(sk5, cur3, cur5 + cur4) * (E5);                        \
    cur4 = (cur4 + cur3) * (EB);                                       \
    cur3 = fmaf(sk3, cur1, cur3 + cur2) * (E3);                        \
    cur2 = (cur2 + cur1) * (EB);                                       \
    cur1 = fmaf(sk1, c7m, cur1 + cur0) * (E1);                         \
    cur0 = (cur0 + c7m) * (EB);                                        \
  } while (0)

#define RENORM do {                                                    \
    curT *= mkT; cur0 *= mk0; cur1 *= mk1; cur2 *= mk2; cur3 *= mk3;   \
    cur4 *= mk4; cur5 *= mk5; cur6 *= mk6; cur7 *= mk7;                \
    float _m = fmaxf(curT, cur0); _m = fmaxf(_m, cur1);                \
    _m = fmaxf(_m, cur2); _m = fmaxf(_m, cur3); _m = fmaxf(_m, cur4);  \
    _m = fmaxf(_m, cur5); _m = fmaxf(_m, cur6); _m = fmaxf(_m, cur7);  \
    _m = wave_max_f(_m);                                               \
    const float _inv = 1.f / fmaxf(_m, 1e-30f);                        \
    log2acc -= log2f(_inv);                                            \
    curT *= _inv; cur0 *= _inv; cur1 *= _inv; cur2 *= _inv;            \
    cur3 *= _inv; cur4 *= _inv; cur5 *= _inv; cur6 *= _inv;            \
    cur7 *= _inv;                                                      \
  } while (0)

// =====================================================================
// NEW PATH kernel 1: fused lse + pre-gather.
// Wave w (= bid*4 + wid, 1024 total) handles rows r = w + 1024k — the EXACT
// lse partition/arithmetic of the previous rounds (partial[] bit-identical).
// For every visited row it additionally writes the exp'd gathered row.
// =====================================================================
__global__ __launch_bounds__(256) void ctc_gather_lse(
    const int*   __restrict__ labels,      // [B, L]
    const float* __restrict__ logits,      // [T, B, V]
    const int*   __restrict__ logit_len,   // [B]
    float*       __restrict__ partial,     // [nLse]
    float*       __restrict__ ggath,       // [B, T, 256]
    float*       __restrict__ bgath,       // [B, T]
    int*         __restrict__ cnt,         // [1] zeroed here for k2
    int T, int B, int L)
{
    const int wid = threadIdx.x >> 6;
    const int l   = threadIdx.x & 63;
    if (blockIdx.x == 0 && threadIdx.x == 0) cnt[0] = 0;

    __shared__ __align__(16) float erow[4][256];   // per-wave scratch row
    float* er = erow[wid];

    const int w  = (int)blockIdx.x * 4 + wid;      // 0..1023
    const int nW = (int)gridDim.x * 4;             // 1024
    const int rows = T * B;
    const int bb = w % B;
    const int Tbb = logit_len[bb];

    const int4 lb4 = ((const int4*)(labels + (size_t)bb * L))[l];
    const int ix = lb4.x, iy = lb4.y, iz = lb4.z, iw = lb4.w;

    float acc = 0.f;
    int r = w;
    if (r < rows) {
        int t = w / B;
        const int ts = nW / B;
        float4 nxt = ((const float4*)(logits + (size_t)r * V))[l];
        while (true) {
            const int rn = r + nW;
            const bool more = rn < rows;
            const float4 x = nxt;
            if (more) nxt = ((const float4*)(logits + (size_t)rn * V))[l];
            // ---- gather side (separate values; lse arithmetic untouched) ---
            float4 e4;
            e4.x = __expf(x.x); e4.y = __expf(x.y);
            e4.z = __expf(x.z); e4.w = __expf(x.w);
            ((float4*)er)[l] = e4;
            // ---- lse (identical ops/order as previous rounds) --------------
            float m = fmaxf(fmaxf(x.x, x.y), fmaxf(x.z, x.w));
            m = wave_max_f(m);
            float ss = __expf(x.x - m) + __expf(x.y - m) +
                       __expf(x.z - m) + __expf(x.w - m);
            ss = wave_sum_f(ss);
            // ---- gather reads (same-wave DS, in-order) ---------------------
            float4 g;
            g.x = er[ix]; g.y = er[iy]; g.z = er[iz]; g.w = er[iw];
            const float gb0 = er[0];
            float* gr = ggath + ((size_t)bb * T + t) * 256;
            ((float4*)gr)[l] = g;
            if (l == 0) bgath[(size_t)bb * T + t] = gb0;
            if (t < Tbb) acc += m + logf(ss);
            if (!more) break;
            r = rn; t += ts;
        }
    }
    if (l == 0) partial[w] = acc;
}

// =====================================================================
// NEW PATH kernel 2: recursion over pre-gathered rows. One wave per b.
// 16-deep named float4 register ring (slot = t&15), blank double-bank.
// No LDS staging, no barriers. Includes exact ctc_final replica.
// =====================================================================
#define GROWC(TROW) (*(const float4*)(gb + 256 * (size_t)((TROW) > Tm1 ? Tm1 : (TROW)) + 4 * l))
#define BROWC(TROW) (*(const float4*)(bb_ + ((TROW) > Tm4 ? Tm4 : (TROW))))

// consume ring slot SL for step TT (blank value ABL), refill with row TT+16
#define KSTEP(TT, SL, ABL) do {                                        \
    MACS((ABL), R##SL.x, R##SL.y, R##SL.z, R##SL.w);                   \
    R##SL = GROWC((TT) + 16);                                          \
  } while (0)

// one 16-step window; K0..K3 are the blank-bank float4 registers (explicit
// parameters — no token pasting, see round-12 note)
#define WIN16(BASE, K0, K1, K2, K3) do {                               \
    KSTEP((BASE) +  0,  0, (K0).x); KSTEP((BASE) +  1,  1, (K0).y);    \
    KSTEP((BASE) +  2,  2, (K0).z); KSTEP((BASE) +  3,  3, (K0).w);    \
    K0 = BROWC((BASE) + 32);                                           \
    KSTEP((BASE) +  4,  4, (K1).x); KSTEP((BASE) +  5,  5, (K1).y);    \
    KSTEP((BASE) +  6,  6, (K1).z); KSTEP((BASE) +  7,  7, (K1).w);    \
    K1 = BROWC((BASE) + 36);                                           \
    KSTEP((BASE) +  8,  8, (K2).x); KSTEP((BASE) +  9,  9, (K2).y);    \
    KSTEP((BASE) + 10, 10, (K2).z); KSTEP((BASE) + 11, 11, (K2).w);    \
    K2 = BROWC((BASE) + 40);                                           \
    KSTEP((BASE) + 12, 12, (K3).x); KSTEP((BASE) + 13, 13, (K3).y);    \
    KSTEP((BASE) + 14, 14, (K3).z); KSTEP((BASE) + 15, 15, (K3).w);    \
    K3 = BROWC((BASE) + 44);                                           \
    RENORM;                                                            \
  } while (0)

// first window: t = 1..15 (bank A, rows 0..15), refill A <- rows 32..47
#define W0FIRST() do {                                                 \
    KSTEP( 1,  1, blkA0.y); KSTEP( 2,  2, blkA0.z); KSTEP( 3,  3, blkA0.w); \
    blkA0 = BROWC(32);                                                 \
    KSTEP( 4,  4, blkA1.x); KSTEP( 5,  5, blkA1.y);                    \
    KSTEP( 6,  6, blkA1.z); KSTEP( 7,  7, blkA1.w);                    \
    blkA1 = BROWC(36);                                                 \
    KSTEP( 8,  8, blkA2.x); KSTEP( 9,  9, blkA2.y);                    \
    KSTEP(10, 10, blkA2.z); KSTEP(11, 11, blkA2.w);                    \
    blkA2 = BROWC(40);                                                 \
    KSTEP(12, 12, blkA3.x); KSTEP(13, 13, blkA3.y);                    \
    KSTEP(14, 14, blkA3.z); KSTEP(15, 15, blkA3.w);                    \
    blkA3 = BROWC(44);                                                 \
    RENORM;                                                            \
  } while (0)

__global__ __launch_bounds__(64) void ctc_rec(
    const int*   __restrict__ labels,      // [B, L]
    const float* __restrict__ logits,      // [T, B, V] (init + tail only)
    const int*   __restrict__ label_len,   // [B]
    const int*   __restrict__ logit_len,   // [B]
    const float* __restrict__ partial,     // [nLse] (from k1)
    const float* __restrict__ ggath,       // [B, T, 256]
    const float* __restrict__ bgath,       // [B, T]
    float*       __restrict__ vbuf,        // [B]
    int*         __restrict__ cnt,         // [1]
    float*       __restrict__ out,         // [1]
    int T, int B, int L, int nLse)
{
    const int l = threadIdx.x;
    const int b = blockIdx.x;
    __shared__ float afin[514];

    const int Tb = logit_len[b];
    const int Lb = label_len[b];
    const int Sb = 2 * Lb + 1;
    const int Tm1 = T - 1;
    const int Tm4 = T - 4;

    const float* lg  = logits + (size_t)b * V;
    const size_t rs  = (size_t)B * V;
    const float* gb  = ggath + (size_t)b * T * 256;
    const float* bb_ = bgath + (size_t)b * T;

    const int4 lb4 = ((const int4*)(labels + (size_t)b * L))[l];
    const int ix = lb4.x, iy = lb4.y, iz = lb4.z, iw = lb4.w;
    const int prevw = __shfl_up(iw, 1);
    const float sk1 = (l > 0 && ix != prevw) ? 1.f : 0.f;
    const float sk3 = (iy != ix) ? 1.f : 0.f;
    const float sk5 = (iz != iy) ? 1.f : 0.f;
    const float sk7 = (iw != iz) ? 1.f : 0.f;

    const float mk0 = (8 * l + 0 < Sb) ? 1.f : 0.f;
    const float mk1 = (8 * l + 1 < Sb) ? 1.f : 0.f;
    const float mk2 = (8 * l + 2 < Sb) ? 1.f : 0.f;
    const float mk3 = (8 * l + 3 < Sb) ? 1.f : 0.f;
    const float mk4 = (8 * l + 4 < Sb) ? 1.f : 0.f;
    const float mk5 = (8 * l + 5 < Sb) ? 1.f : 0.f;
    const float mk6 = (8 * l + 6 < Sb) ? 1.f : 0.f;
    const float mk7 = (8 * l + 7 < Sb) ? 1.f : 0.f;
    const float mkT = (Sb > 512 && l == 63) ? 1.f : 0.f;

    // t=0 init (identical to previous rounds)
    float cur0 = 0.f, cur1 = 0.f, cur2 = 0.f, cur3 = 0.f;
    float cur4 = 0.f, cur5 = 0.f, cur6 = 0.f, cur7 = 0.f, curT = 0.f;
    if (l == 0) {
        cur0 = __expf(lg[0]);
        cur1 = __expf(lg[ix]) * mk1;
    }
    float log2acc = 0.f;

    int base = 1;
    if (Tb >= 16) {
        // ring prefill: slot t&15 holds row t; R0 <- row 16
        float4 R0, R1, R2, R3, R4, R5, R6, R7;
        float4 R8, R9, R10, R11, R12, R13, R14, R15;
        R1  = GROWC(1);  R2  = GROWC(2);  R3  = GROWC(3);  R4  = GROWC(4);
        R5  = GROWC(5);  R6  = GROWC(6);  R7  = GROWC(7);  R8  = GROWC(8);
        R9  = GROWC(9);  R10 = GROWC(10); R11 = GROWC(11); R12 = GROWC(12);
        R13 = GROWC(13); R14 = GROWC(14); R15 = GROWC(15); R0  = GROWC(16);
        // blank banks: A = rows 0..15, B = rows 16..31
        float4 blkA0 = BROWC(0),  blkA1 = BROWC(4);
        float4 blkA2 = BROWC(8),  blkA3 = BROWC(12);
        float4 blkB0 = BROWC(16), blkB1 = BROWC(20);
        float4 blkB2 = BROWC(24), blkB3 = BROWC(28);

        W0FIRST();                          // t=1..15, renorm at t=15
        int wv = 1;
        for (base = 16; base + 16 <= Tb; base += 16, ++wv) {
            if (wv & 1) WIN16(base, blkB0, blkB1, blkB2, blkB3);
            else        WIN16(base, blkA0, blkA1, blkA2, blkA3);
        }
    }
    // scalar tail (t = base..Tb-1): raw logits, identical numerics
    for (int t = base; t < Tb; ++t) {
        const float* rowp = lg + rs * (size_t)t;
        const float eb = __expf(rowp[0]);
        const float e1 = __expf(rowp[ix]), e3 = __expf(rowp[iy]);
        const float e5 = __expf(rowp[iz]), e7 = __expf(rowp[iw]);
        MACS(eb, e1, e3, e5, e7);
    }

    // readout: ln(a[end] + a[end-1]) + ln2*log2acc
    afin[8 * l + 0] = cur0; afin[8 * l + 1] = cur1;
    afin[8 * l + 2] = cur2; afin[8 * l + 3] = cur3;
    afin[8 * l + 4] = cur4; afin[8 * l + 5] = cur5;
    afin[8 * l + 6] = cur6; afin[8 * l + 7] = cur7;
    if (l == 63) afin[512] = curT;
    const int end = 2 * Lb;
    const int em1 = (end > 0) ? end - 1 : 0;
    float ssum = afin[end] + afin[em1];     // same-wave DS, in-order
    ssum = fmaxf(ssum, 1e-37f);
    const float lnt = logf(ssum) + LN2_F * log2acc;

    // ---- exact ctc_final replica, distributed ---------------------------
    float c = 0.f;
    for (int k = b; k < nLse; k += B) c += partial[k];
    const float v = c - lnt;

    int old = 0;
    if (l == 0) {
        atomicExch(&vbuf[b], v);
        __threadfence();
        old = atomicAdd(cnt, 1);
    }
    old = __shfl(old, 0, 64);
    if (old == B - 1) {                     // last block: final butterfly
        __threadfence();
        float vv = atomicAdd(&vbuf[l], 0.0f);   // coherent read of v_l
        #pragma unroll
        for (int o = 32; o >= 1; o >>= 1) vv += __shfl_xor(vv, o, 64);
        if (l == 0) out[0] = vv / (float)B;
    }
}

// =====================================================================
// FALLBACK PATH (round-10 kernels, verbatim): used if ws_size is too small
// =====================================================================
#define PRE(N, S) do {                                                 \
    G##N = *(const float4*)(&gbuf[h][S][l][0]);                        \
    A##N = bbuf[h][S];                                                 \
  } while (0)
#define STEPR(N, S) do {                                               \
    MACS(A##N, G##N.x, G##N.y, G##N.z, G##N.w);                        \
    PRE(N, S);                                                         \
  } while (0)
#define STEPC(N) MACS(A##N, G##N.x, G##N.y, G##N.z, G##N.w)

#define PLOAD(dst, WV, J)                                              \
    dst = *(const float4*)(lg + rs * (size_t)(16 * (WV) + p + 7 * (J)) + 4 * l)
#define PROC(XV, i) do {                                               \
    float4 _e;                                                         \
    _e.x = __expf((XV).x); _e.y = __expf((XV).y);                      \
    _e.z = __expf((XV).z); _e.w = __expf((XV).w);                      \
    *(float4*)&prow[p][4 * l] = _e;                                    \
    const float* _pr = prow[p];                                        \
    float _gb = _pr[0];                                                \
    float4 _gv;                                                        \
    _gv.x = _pr[ix]; _gv.y = _pr[iy]; _gv.z = _pr[iz]; _gv.w = _pr[iw];\
    *(float4*)&gbuf[h][i][l][0] = _gv;                                 \
    if (l == 0) bbuf[h][i] = _gb;                                      \
  } while (0)

#define WG_BARRIER asm volatile("s_waitcnt lgkmcnt(0)\n\ts_barrier" ::: "memory")

__global__ __launch_bounds__(512) void ctc_main(
    const int*   __restrict__ labels,
    const float* __restrict__ logits,
    const int*   __restrict__ label_len,
    const int*   __restrict__ logit_len,
    float*       __restrict__ partial,
    float*       __restrict__ lnterm,
    int T, int B, int L)
{
    const int tid = threadIdx.x;
    const int wid = tid >> 6;
    const int l   = tid & 63;

    if ((int)blockIdx.x < B) {
        __shared__ __align__(16) float gbuf[2][16][64][4];
        __shared__ float bbuf[2][16];
        __shared__ __align__(16) float prow[7][256];
        __shared__ float afin[514];

        const int b = blockIdx.x;
        const int Tb = logit_len[b];
        const int Lb = label_len[b];
        const int Sb = 2 * Lb + 1;

        const float* lg = logits + (size_t)b * V;
        const size_t rs = (size_t)B * V;

        const int4 lb4 = ((const int4*)(labels + (size_t)b * L))[l];
        const int ix = lb4.x, iy = lb4.y, iz = lb4.z, iw = lb4.w;
        const int prevw = __shfl_up(iw, 1);
        const float sk1 = (l > 0 && ix != prevw) ? 1.f : 0.f;
        const float sk3 = (iy != ix) ? 1.f : 0.f;
        const float sk5 = (iz != iy) ? 1.f : 0.f;
        const float sk7 = (iw != iz) ? 1.f : 0.f;

        const float mk0 = (8 * l + 0 < Sb) ? 1.f : 0.f;
        const float mk1 = (8 * l + 1 < Sb) ? 1.f : 0.f;
        const float mk2 = (8 * l + 2 < Sb) ? 1.f : 0.f;
        const float mk3 = (8 * l + 3 < Sb) ? 1.f : 0.f;
        const float mk4 = (8 * l + 4 < Sb) ? 1.f : 0.f;
        const float mk5 = (8 * l + 5 < Sb) ? 1.f : 0.f;
        const float mk6 = (8 * l + 6 < Sb) ? 1.f : 0.f;
        const float mk7 = (8 * l + 7 < Sb) ? 1.f : 0.f;
        const float mkT = (Sb > 512 && l == 63) ? 1.f : 0.f;

        float cur0 = 0.f, cur1 = 0.f, cur2 = 0.f, cur3 = 0.f;
        float cur4 = 0.f, cur5 = 0.f, cur6 = 0.f, cur7 = 0.f, curT = 0.f;
        if (l == 0) {
            cur0 = __expf(lg[0]);
            cur1 = __expf(lg[ix]) * mk1;
        }
        float log2acc = 0.f;

        const int NW = Tb / 16;

        float4 G0{}, G1{}, G2{}, G3{}, G4{}, G5{}, G6{}, G7{};
        float  A0 = 0, A1 = 0, A2 = 0, A3 = 0, A4 = 0, A5 = 0, A6 = 0, A7 = 0;

        const int p = (wid > 0) ? wid - 1 : 0;
        const bool three = (p < 2);
        float4 ca{}, cb{}, cc{}, na{}, nb{}, nc{};
        if (wid > 0 && NW > 0) {
            PLOAD(ca, 0, 0);
            PLOAD(cb, 0, 1);
            if (three) PLOAD(cc, 0, 2);
        }
        if (wid == 0) __builtin_amdgcn_s_setprio(1);

        for (int k = 0; k <= NW; ++k) {
            if (wid != 0) {
                if (k < NW) {
                    const int h = k & 1;
                    if (k + 1 < NW) {
                        PLOAD(na, k + 1, 0);
                        PLOAD(nb, k + 1, 1);
                        if (three) PLOAD(nc, k + 1, 2);
                    }
                    PROC(ca, p);
                    PROC(cb, p + 7);
                    if (three) PROC(cc, p + 14);
                    ca = na; cb = nb; cc = nc;
                }
            } else if (k >= 1) {
                const int w = k - 1;
                const int h = w & 1;
                if (w == 0) {
                    PRE(1, 1); PRE(2, 2); PRE(3, 3); PRE(4, 4);
                    PRE(5, 5); PRE(6, 6); PRE(7, 7); PRE(0, 8);
                    STEPR(1, 9);  STEPR(2, 10); STEPR(3, 11); STEPR(4, 12);
                    STEPR(5, 13); STEPR(6, 14); STEPR(7, 15);
                    STEPC(0);
                    STEPC(1); STEPC(2); STEPC(3); STEPC(4);
                    STEPC(5); STEPC(6); STEPC(7);
                } else {
                    PRE(0, 0); PRE(1, 1); PRE(2, 2); PRE(3, 3);
                    PRE(4, 4); PRE(5, 5); PRE(6, 6); PRE(7, 7);
                    STEPR(0, 8);  STEPR(1, 9);  STEPR(2, 10); STEPR(3, 11);
                    STEPR(4, 12); STEPR(5, 13); STEPR(6, 14); STEPR(7, 15);
                    STEPC(0); STEPC(1); STEPC(2); STEPC(3);
                    STEPC(4); STEPC(5); STEPC(6); STEPC(7);
                }
                RENORM;
            }
            WG_BARRIER;
        }

        if (wid == 0) {
            for (int t = 16 * NW; t < Tb; ++t) {
                if (t < 1) continue;
                const float* rowp = lg + rs * (size_t)t;
                const float eb = __expf(rowp[0]);
                const float e1 = __expf(rowp[ix]), e3 = __expf(rowp[iy]);
                const float e5 = __expf(rowp[iz]), e7 = __expf(rowp[iw]);
                MACS(eb, e1, e3, e5, e7);
            }

            afin[8 * l + 0] = cur0; afin[8 * l + 1] = cur1;
            afin[8 * l + 2] = cur2; afin[8 * l + 3] = cur3;
            afin[8 * l + 4] = cur4; afin[8 * l + 5] = cur5;
            afin[8 * l + 6] = cur6; afin[8 * l + 7] = cur7;
            if (l == 63) afin[512] = curT;
            const int end = 2 * Lb;
            const int em1 = (end > 0) ? end - 1 : 0;
            float ssum = afin[end] + afin[em1];
            ssum = fmaxf(ssum, 1e-37f);
            if (l == 0) lnterm[b] = logf(ssum) + LN2_F * log2acc;
        }
    } else {
        const int w  = ((int)blockIdx.x - B) * 8 + wid;
        const int nW = ((int)gridDim.x - B) * 8;
        const int rows = T * B;
        const int bb = w % B;
        const int Tbb = logit_len[bb];
        float acc = 0.f;
        int r = w;
        if (r < rows) {
            int t = w / B;
            const int ts = nW / B;
            float4 nxt = ((const float4*)(logits + (size_t)r * V))[l];
            while (true) {
                const int rn = r + nW;
                const bool more = rn < rows;
                const float4 x = nxt;
                if (more) nxt = ((const float4*)(logits + (size_t)rn * V))[l];
                float m = fmaxf(fmaxf(x.x, x.y), fmaxf(x.z, x.w));
                m = wave_max_f(m);
                float ss = __expf(x.x - m) + __expf(x.y - m) +
                           __expf(x.z - m) + __expf(x.w - m);
                ss = wave_sum_f(ss);
                if (t < Tbb) acc += m + logf(ss);
                if (!more) break;
                r = rn; t += ts;
            }
        }
        if (l == 0) partial[w] = acc;
    }
}

__global__ __launch_bounds__(64) void ctc_final(
    const float* __restrict__ partial,
    const float* __restrict__ lnterm,
    float* __restrict__ out, int B, int nW)
{
    const int b = threadIdx.x;
    float v = 0.f;
    if (b < B) {
        float c = 0.f;
        for (int k = b; k < nW; k += B) c += partial[k];
        v = c - lnterm[b];
    }
    #pragma unroll
    for (int o = 32; o >= 1; o >>= 1) v += __shfl_xor(v, o, 64);
    if (threadIdx.x == 0) out[0] = v / (float)B;
}

extern "C" void kernel_launch(void* const* d_in, const int* in_sizes, int n_in,
                              void* d_out, int out_size, void* d_ws, size_t ws_size,
                              hipStream_t stream) {
    const int*   labels    = (const int*)d_in[0];
    const float* logits    = (const float*)d_in[1];
    const int*   label_len = (const int*)d_in[2];
    const int*   logit_len = (const int*)d_in[3];

    const int B = in_sizes[2];                 // 64
    const int L = in_sizes[0] / B;             // 256
    const int T = in_sizes[1] / (B * V);       // 1024

    const int nLse = 1024;

    // workspace carve for the two-pass path
    const size_t ggathN = (size_t)B * T * 256;       // floats
    const size_t bgathN = (size_t)B * T;             // floats
    const size_t need   = (ggathN + bgathN + nLse + B + 16) * sizeof(float);

    if (ws_size >= need) {
        float* ggath   = (float*)d_ws;
        float* bgath   = ggath + ggathN;
        float* partial = bgath + bgathN;
        float* vbuf    = partial + nLse;
        int*   cnt     = (int*)(vbuf + B);

        ctc_gather_lse<<<256, 256, 0, stream>>>(labels, logits, logit_len,
                                                partial, ggath, bgath, cnt,
                                                T, B, L);
        ctc_rec<<<B, 64, 0, stream>>>(labels, logits, label_len, logit_len,
                                      partial, ggath, bgath, vbuf, cnt,
                                      (float*)d_out, T, B, L, nLse);
    } else {
        // fallback: round-10 path
        float* partial = (float*)d_ws;             // [nLse]
        float* lnterm  = partial + nLse;           // [B]
        ctc_main<<<B + nLse / 8, 512, 0, stream>>>(labels, logits, label_len,
                                                   logit_len, partial, lnterm,
                                                   T, B, L);
        ctc_final<<<1, 64, 0, stream>>>(partial, lnterm, (float*)d_out, B, nLse);
    }
}